// Round 2
// baseline (323.906 us; speedup 1.0000x reference)
//
#include <hip/hip_runtime.h>
#include <math.h>

#define TB 2
#define TT 2048
#define NH 16
#define HD 64
#define HSZ 1024

typedef float floatx4 __attribute__((ext_vector_type(4)));
typedef __bf16 bf16x8 __attribute__((ext_vector_type(8)));

#define LOG2E  1.4426950408889634f
#define NEGF   (-0.4152410118609203f)   // -log2(10000)/32
#define INV2PI 0.15915494309189535f

// ---------- phase 1a: RoPE K -> bf16 Kr[b][h][t][d] ----------
__global__ __launch_bounds__(256)
void rope_k_kernel(const float* __restrict__ K, __bf16* __restrict__ Kr) {
    int i = blockIdx.x * 256 + threadIdx.x;   // over B*T*NH*32 pairs
    int d = i & 31;
    int h = (i >> 5) & 15;
    int t = (i >> 9) & 2047;
    int b = i >> 20;
    const float* src = K + ((size_t)(b * TT + t) * HSZ) + h * HD + d;
    float x0 = src[0], x1 = src[32];
    float freq = exp2f((float)d * NEGF);
    float rv = (float)t * freq * INV2PI;
    rv -= floorf(rv);
    float s = __builtin_amdgcn_sinf(rv);
    float c = __builtin_amdgcn_cosf(rv);
    __bf16* dst = Kr + ((size_t)((b * NH + h) * TT + t) * HD) + d;
    dst[0]  = (__bf16)(x0 * c - x1 * s);
    dst[32] = (__bf16)(x1 * c + x0 * s);
}

// ---------- phase 1b: transpose V -> bf16 Vt[b][h][d][t] ----------
__global__ __launch_bounds__(256)
void vt_kernel(const float* __restrict__ V, __bf16* __restrict__ Vt) {
    __shared__ __bf16 lt[64][72];
    int blk = blockIdx.x;               // B*NH*(T/64) = 1024
    int ttile = blk & 31;
    int bh = blk >> 5;
    int b = bh >> 4, h = bh & 15;
    int tid = threadIdx.x;
    int tl = tid >> 2, dg = (tid & 3) * 16;
    const float* vrow = V + ((size_t)(b * TT + ttile * 64 + tl) * HSZ) + h * HD + dg;
    floatx4 v0 = *(const floatx4*)&vrow[0];
    floatx4 v1 = *(const floatx4*)&vrow[4];
    floatx4 v2 = *(const floatx4*)&vrow[8];
    floatx4 v3 = *(const floatx4*)&vrow[12];
    #pragma unroll
    for (int j = 0; j < 4; ++j) {
        lt[tl][dg + j]      = (__bf16)v0[j];
        lt[tl][dg + 4 + j]  = (__bf16)v1[j];
        lt[tl][dg + 8 + j]  = (__bf16)v2[j];
        lt[tl][dg + 12 + j] = (__bf16)v3[j];
    }
    __syncthreads();
    int dl = tid >> 2, tg = (tid & 3) * 16;
    bf16x8 o0, o1;
    #pragma unroll
    for (int j = 0; j < 8; ++j) { o0[j] = lt[tg + j][dl]; o1[j] = lt[tg + 8 + j][dl]; }
    __bf16* dst = Vt + ((size_t)(bh * HD + dl) * TT) + ttile * 64 + tg;
    *(bf16x8*)&dst[0] = o0;
    *(bf16x8*)&dst[8] = o1;
}

// ---------- phase 2: barrier-free flash attention ----------
__global__ __launch_bounds__(256)
void attn_kernel(const float* __restrict__ Q, const __bf16* __restrict__ Kr,
                 const __bf16* __restrict__ Vt, float* __restrict__ Out) {
    int blk = blockIdx.x;               // B*NH*(T/64) = 1024
    int qtile = blk & 31;
    int bh = blk >> 5;
    int b = bh >> 4, h = bh & 15;
    int tid = threadIdx.x;
    int wave = tid >> 6, lane = tid & 63;
    int lane15 = lane & 15, quad = lane >> 4;

    // per-wave P round-trip tile only; no __syncthreads anywhere
    __shared__ __align__(16) __bf16 sP[4][16][72];

    const float scale2 = 0.125f * LOG2E;                       // 1/sqrt(64) * log2e
    const float slope2 = exp2f(-0.5f * (float)(h + 1)) * LOG2E;

    // ---- Q load + RoPE into A fragments (scale folded; base-2 domain) ----
    int t_q = qtile * 64 + wave * 16 + lane15;
    int d0 = quad * 8;
    const float* qrow = Q + ((size_t)(b * TT + t_q) * HSZ) + h * HD;
    float q0[8], q1[8];
    *(floatx4*)&q0[0] = *(const floatx4*)&qrow[d0];
    *(floatx4*)&q0[4] = *(const floatx4*)&qrow[d0 + 4];
    *(floatx4*)&q1[0] = *(const floatx4*)&qrow[d0 + 32];
    *(floatx4*)&q1[4] = *(const floatx4*)&qrow[d0 + 36];
    bf16x8 aQ0, aQ1;
    #pragma unroll
    for (int j = 0; j < 8; ++j) {
        float freq = exp2f((float)(d0 + j) * NEGF);
        float rv = (float)t_q * freq * INV2PI;
        rv -= floorf(rv);
        float s = __builtin_amdgcn_sinf(rv);
        float c = __builtin_amdgcn_cosf(rv);
        aQ0[j] = (__bf16)((q0[j] * c - q1[j] * s) * scale2);
        aQ1[j] = (__bf16)((q1[j] * c + q0[j] * s) * scale2);
    }

    float slk[4];
    #pragma unroll
    for (int nt = 0; nt < 4; ++nt) slk[nt] = slope2 * (float)(nt * 16 + lane15);

    floatx4 O0 = {0.f,0.f,0.f,0.f}, O1 = O0, O2 = O0, O3 = O0;
    float mrow[4] = {-INFINITY, -INFINITY, -INFINITY, -INFINITY};
    float lrow[4] = {0.f, 0.f, 0.f, 0.f};

    const __bf16* Krb = Kr + (size_t)bh * TT * HD;
    const __bf16* Vtb = Vt + (size_t)bh * HD * TT;

    for (int kt = 0; kt < TT / 64; ++kt) {
        int k0 = kt * 64;
        float sl_k0 = slope2 * (float)k0;

        // ---- QK^T: 16q x 64k scores (8 MFMA), bias = slope2*k (row const dropped) ----
        float Sv[4][4];
        #pragma unroll
        for (int nt = 0; nt < 4; ++nt) {
            const __bf16* krow = Krb + (size_t)(k0 + nt * 16 + lane15) * HD;
            bf16x8 bK0 = *(const bf16x8*)&krow[quad * 8];
            bf16x8 bK1 = *(const bf16x8*)&krow[32 + quad * 8];
            floatx4 acc = {0.f,0.f,0.f,0.f};
            acc = __builtin_amdgcn_mfma_f32_16x16x32_bf16(aQ0, bK0, acc, 0, 0, 0);
            acc = __builtin_amdgcn_mfma_f32_16x16x32_bf16(aQ1, bK1, acc, 0, 0, 0);
            float bias = slk[nt] + sl_k0;
            #pragma unroll
            for (int r = 0; r < 4; ++r) Sv[nt][r] = acc[r] + bias;
        }

        // ---- online softmax (base-2), row = quad*4+r, 16 lanes/row ----
        #pragma unroll
        for (int r = 0; r < 4; ++r) {
            float mx = fmaxf(fmaxf(Sv[0][r], Sv[1][r]), fmaxf(Sv[2][r], Sv[3][r]));
            mx = fmaxf(mx, __shfl_xor(mx, 1));
            mx = fmaxf(mx, __shfl_xor(mx, 2));
            mx = fmaxf(mx, __shfl_xor(mx, 4));
            mx = fmaxf(mx, __shfl_xor(mx, 8));
            float mnew = fmaxf(mrow[r], mx);
            float alpha = __builtin_amdgcn_exp2f(mrow[r] - mnew);  // first iter: 0
            mrow[r] = mnew;
            float p0 = __builtin_amdgcn_exp2f(Sv[0][r] - mnew);
            float p1 = __builtin_amdgcn_exp2f(Sv[1][r] - mnew);
            float p2 = __builtin_amdgcn_exp2f(Sv[2][r] - mnew);
            float p3 = __builtin_amdgcn_exp2f(Sv[3][r] - mnew);
            lrow[r] = lrow[r] * alpha + (p0 + p1 + p2 + p3);       // lane-local partial
            O0[r] *= alpha; O1[r] *= alpha; O2[r] *= alpha; O3[r] *= alpha;
            int row = quad * 4 + r;
            sP[wave][row][lane15]      = (__bf16)p0;
            sP[wave][row][16 + lane15] = (__bf16)p1;
            sP[wave][row][32 + lane15] = (__bf16)p2;
            sP[wave][row][48 + lane15] = (__bf16)p3;
        }

        // ---- PV: O[16q][64d] += P(16x64) * V(64x64), 8 MFMA ----
        #pragma unroll
        for (int half = 0; half < 2; ++half) {
            bf16x8 aP = *(const bf16x8*)&sP[wave][lane15][half * 32 + quad * 8];
            const __bf16* vbase = Vtb + k0 + half * 32 + quad * 8;
            bf16x8 bV0 = *(const bf16x8*)&vbase[(size_t)( 0 + lane15) * TT];
            bf16x8 bV1 = *(const bf16x8*)&vbase[(size_t)(16 + lane15) * TT];
            bf16x8 bV2 = *(const bf16x8*)&vbase[(size_t)(32 + lane15) * TT];
            bf16x8 bV3 = *(const bf16x8*)&vbase[(size_t)(48 + lane15) * TT];
            O0 = __builtin_amdgcn_mfma_f32_16x16x32_bf16(aP, bV0, O0, 0, 0, 0);
            O1 = __builtin_amdgcn_mfma_f32_16x16x32_bf16(aP, bV1, O1, 0, 0, 0);
            O2 = __builtin_amdgcn_mfma_f32_16x16x32_bf16(aP, bV2, O2, 0, 0, 0);
            O3 = __builtin_amdgcn_mfma_f32_16x16x32_bf16(aP, bV3, O3, 0, 0, 0);
        }
    }

    // ---- epilogue: reduce l across 16 lanes, normalize, store fp32 ----
    int q_glb = qtile * 64 + wave * 16 + quad * 4;
    #pragma unroll
    for (int r = 0; r < 4; ++r) {
        float l = lrow[r];
        l += __shfl_xor(l, 1);
        l += __shfl_xor(l, 2);
        l += __shfl_xor(l, 4);
        l += __shfl_xor(l, 8);
        float inv = 1.0f / l;
        size_t base = ((size_t)(b * TT + q_glb + r) * HSZ) + h * HD + lane15;
        Out[base +  0] = O0[r] * inv;
        Out[base + 16] = O1[r] * inv;
        Out[base + 32] = O2[r] * inv;
        Out[base + 48] = O3[r] * inv;
    }
}

extern "C" void kernel_launch(void* const* d_in, const int* in_sizes, int n_in,
                              void* d_out, int out_size, void* d_ws, size_t ws_size,
                              hipStream_t stream) {
    const float* q = (const float*)d_in[0];
    const float* k = (const float*)d_in[1];
    const float* v = (const float*)d_in[2];
    float* out = (float*)d_out;

    __bf16* Kr = (__bf16*)d_ws;                        // 8 MB
    __bf16* Vt = Kr + (size_t)TB * NH * TT * HD;       // +8 MB

    rope_k_kernel<<<dim3((TB * TT * NH * 32) / 256), 256, 0, stream>>>(k, Kr);
    vt_kernel<<<dim3(TB * NH * (TT / 64)), 256, 0, stream>>>(v, Vt);
    attn_kernel<<<dim3(TB * NH * (TT / 64)), 256, 0, stream>>>(q, Kr, Vt, out);
}

// Round 3
// 166.718 us; speedup vs baseline: 1.9428x; 1.9428x over previous
//
#include <hip/hip_runtime.h>
#include <math.h>

#define TB 2
#define TT 2048
#define NH 16
#define HD 64
#define HSZ 1024

typedef float floatx4 __attribute__((ext_vector_type(4)));
typedef __bf16 bf16x4 __attribute__((ext_vector_type(4)));
typedef __bf16 bf16x8 __attribute__((ext_vector_type(8)));

#define LOG2E  1.4426950408889634f
#define NEGF   (-0.4152410118609203f)   // -log2(10000)/32
#define INV2PI 0.15915494309189535f

// ============ phase 1a: RoPE K -> fragment-major packed bf16 ============
// Kp granule per (bh,kt,nt): 2 blocks of 512 bf16 (1 KB each).
// Entry lane=q*16+r holds dims [blk*32+8q, +8) of key t = kt*64 + 4r + nt.
__global__ __launch_bounds__(256)
void rope_k_pack(const float* __restrict__ K, __bf16* __restrict__ Kp) {
    int i = blockIdx.x * 256 + threadIdx.x;   // B*T*NH*32 = 2^21 threads
    int d = i & 31;
    int h = (i >> 5) & 15;
    int t = (i >> 9) & 2047;
    int b = i >> 20;
    const float* src = K + ((size_t)(b * TT + t) * HSZ) + h * HD + d;
    float x0 = src[0], x1 = src[32];
    float freq = exp2f((float)d * NEGF);
    float rv = (float)t * freq * INV2PI;
    rv -= floorf(rv);
    float s = __builtin_amdgcn_sinf(rv);
    float c = __builtin_amdgcn_cosf(rv);
    float y0 = x0 * c - x1 * s;               // dim d
    float y1 = x1 * c + x0 * s;               // dim d+32
    int bh = b * NH + h;
    int kt = t >> 6, r = (t >> 2) & 15, nt = t & 3;
    int q = d >> 3, j = d & 7;
    size_t base = ((size_t)((bh * 32 + kt) * 4 + nt)) * 1024 + (size_t)(q * 16 + r) * 8 + j;
    Kp[base]       = (__bf16)y0;
    Kp[base + 512] = (__bf16)y1;
}

// ============ phase 1b: V -> fragment-major packed bf16 ============
// Vp granule per (bh,kt,h2,g): 512 bf16 (1 KB). Entry lane=q*16+r holds
// V[key = kt*64 + h2*32 + 8q + j][dim = g*16 + r], j=0..7.
__global__ __launch_bounds__(256)
void v_pack(const float* __restrict__ V, __bf16* __restrict__ Vp) {
    __shared__ __bf16 lt[64][72];
    int blk = blockIdx.x;               // bh*32 + kt, 1024 blocks
    int kt = blk & 31;
    int bh = blk >> 5;
    int b = bh >> 4, h = bh & 15;
    int tid = threadIdx.x;
    int tl = tid >> 2, dg = (tid & 3) * 16;
    const float* vrow = V + ((size_t)(b * TT + kt * 64 + tl) * HSZ) + h * HD + dg;
    floatx4 v0 = *(const floatx4*)&vrow[0];
    floatx4 v1 = *(const floatx4*)&vrow[4];
    floatx4 v2 = *(const floatx4*)&vrow[8];
    floatx4 v3 = *(const floatx4*)&vrow[12];
    #pragma unroll
    for (int j = 0; j < 4; ++j) {
        lt[tl][dg + j]      = (__bf16)v0[j];
        lt[tl][dg + 4 + j]  = (__bf16)v1[j];
        lt[tl][dg + 8 + j]  = (__bf16)v2[j];
        lt[tl][dg + 12 + j] = (__bf16)v3[j];
    }
    __syncthreads();
    #pragma unroll
    for (int ss = 0; ss < 2; ++ss) {
        int s = tid + ss * 256;          // 0..511 segments of 16 B
        int hg = s >> 6;                 // h2*4 + g
        int l = s & 63;
        int q = l >> 4, r = l & 15;
        int h2 = hg >> 2, g = hg & 3;
        bf16x8 o;
        #pragma unroll
        for (int j = 0; j < 8; ++j) o[j] = lt[h2 * 32 + q * 8 + j][g * 16 + r];
        *(bf16x8*)(Vp + (size_t)blk * 4096 + (size_t)hg * 512 + (size_t)l * 8) = o;
    }
}

// ============ phase 2: barrier-free flash attention, static max ============
__global__ __launch_bounds__(256)
void attn_kernel(const float* __restrict__ Q, const __bf16* __restrict__ Kp,
                 const __bf16* __restrict__ Vp, float* __restrict__ Out) {
    int blk = blockIdx.x;               // B*NH*(T/64) = 1024
    int qtile = blk & 31;
    int bh = blk >> 5;
    int b = bh >> 4, h = bh & 15;
    int tid = threadIdx.x;
    int wave = tid >> 6, lane = tid & 63;
    int lane15 = lane & 15, quad = lane >> 4;

    __shared__ __align__(16) __bf16 sP[4][16][72];  // per-wave P round-trip only

    const float scale2 = 0.125f * LOG2E;
    const float slope2 = exp2f(-0.5f * (float)(h + 1)) * LOG2E;
    const float ms     = slope2 * 2047.0f + 20.0f;  // static log2-domain shift

    // ---- Q load + RoPE into A fragments ----
    int t_q = qtile * 64 + wave * 16 + lane15;
    int d0 = quad * 8;
    const float* qrow = Q + ((size_t)(b * TT + t_q) * HSZ) + h * HD;
    float q0[8], q1[8];
    *(floatx4*)&q0[0] = *(const floatx4*)&qrow[d0];
    *(floatx4*)&q0[4] = *(const floatx4*)&qrow[d0 + 4];
    *(floatx4*)&q1[0] = *(const floatx4*)&qrow[d0 + 32];
    *(floatx4*)&q1[4] = *(const floatx4*)&qrow[d0 + 36];
    bf16x8 aQ0, aQ1;
    #pragma unroll
    for (int j = 0; j < 8; ++j) {
        float freq = exp2f((float)(d0 + j) * NEGF);
        float rv = (float)t_q * freq * INV2PI;
        rv -= floorf(rv);
        float s = __builtin_amdgcn_sinf(rv);
        float c = __builtin_amdgcn_cosf(rv);
        aQ0[j] = (__bf16)((q0[j] * c - q1[j] * s) * scale2);
        aQ1[j] = (__bf16)((q1[j] * c + q0[j] * s) * scale2);
    }

    // per-lane bias for key = 4*lane15 + nt, static shift folded in
    float slk2[4];
    #pragma unroll
    for (int nt = 0; nt < 4; ++nt)
        slk2[nt] = slope2 * (float)(4 * lane15 + nt) - ms;
    float sl_k0 = 0.0f;
    const float dstep = slope2 * 64.0f;

    floatx4 O0 = {0.f,0.f,0.f,0.f}, O1 = O0, O2 = O0, O3 = O0;
    float lrow[4] = {0.f, 0.f, 0.f, 0.f};

    const __bf16* Kb = Kp + (size_t)bh * (TT * HD);
    const __bf16* Vb = Vp + (size_t)bh * (TT * HD);

    for (int kt = 0; kt < TT / 64; ++kt) {
        const __bf16* kbase = Kb + (size_t)kt * 4096 + (size_t)lane * 8;
        const __bf16* vbase = Vb + (size_t)kt * 4096 + (size_t)lane * 8;

        // ---- coalesced fragment loads (1 KB per instruction) ----
        bf16x8 bk[4][2];
        #pragma unroll
        for (int nt = 0; nt < 4; ++nt) {
            bk[nt][0] = *(const bf16x8*)(kbase + nt * 1024);
            bk[nt][1] = *(const bf16x8*)(kbase + nt * 1024 + 512);
        }
        bf16x8 bv[2][4];
        #pragma unroll
        for (int hg = 0; hg < 8; ++hg)
            bv[hg >> 2][hg & 3] = *(const bf16x8*)(vbase + hg * 512);

        // ---- QK^T + bias + exp2 (no running max) ----
        float P[4][4];
        #pragma unroll
        for (int nt = 0; nt < 4; ++nt) {
            floatx4 acc = {0.f,0.f,0.f,0.f};
            acc = __builtin_amdgcn_mfma_f32_16x16x32_bf16(aQ0, bk[nt][0], acc, 0, 0, 0);
            acc = __builtin_amdgcn_mfma_f32_16x16x32_bf16(aQ1, bk[nt][1], acc, 0, 0, 0);
            float bias = slk2[nt] + sl_k0;
            #pragma unroll
            for (int r = 0; r < 4; ++r)
                P[nt][r] = __builtin_amdgcn_exp2f(acc[r] + bias);
        }
        sl_k0 += dstep;

        // ---- P -> LDS (one b64 per row), accumulate row sums ----
        #pragma unroll
        for (int r = 0; r < 4; ++r) {
            lrow[r] += (P[0][r] + P[1][r]) + (P[2][r] + P[3][r]);
            bf16x4 pp;
            pp[0] = (__bf16)P[0][r]; pp[1] = (__bf16)P[1][r];
            pp[2] = (__bf16)P[2][r]; pp[3] = (__bf16)P[3][r];
            *(bf16x4*)&sP[wave][quad * 4 + r][4 * lane15] = pp;
        }

        // ---- PV: O[16q][64d] += P(16x64) * V(64x64) ----
        #pragma unroll
        for (int h2 = 0; h2 < 2; ++h2) {
            bf16x8 aP = *(const bf16x8*)&sP[wave][lane15][h2 * 32 + quad * 8];
            O0 = __builtin_amdgcn_mfma_f32_16x16x32_bf16(aP, bv[h2][0], O0, 0, 0, 0);
            O1 = __builtin_amdgcn_mfma_f32_16x16x32_bf16(aP, bv[h2][1], O1, 0, 0, 0);
            O2 = __builtin_amdgcn_mfma_f32_16x16x32_bf16(aP, bv[h2][2], O2, 0, 0, 0);
            O3 = __builtin_amdgcn_mfma_f32_16x16x32_bf16(aP, bv[h2][3], O3, 0, 0, 0);
        }
    }

    // ---- epilogue: reduce l across 16 lanes, normalize, store ----
    int q_glb = qtile * 64 + wave * 16 + quad * 4;
    #pragma unroll
    for (int r = 0; r < 4; ++r) {
        float l = lrow[r];
        l += __shfl_xor(l, 1);
        l += __shfl_xor(l, 2);
        l += __shfl_xor(l, 4);
        l += __shfl_xor(l, 8);
        float inv = 1.0f / l;
        size_t base = ((size_t)(b * TT + q_glb + r) * HSZ) + h * HD + lane15;
        Out[base +  0] = O0[r] * inv;
        Out[base + 16] = O1[r] * inv;
        Out[base + 32] = O2[r] * inv;
        Out[base + 48] = O3[r] * inv;
    }
}

extern "C" void kernel_launch(void* const* d_in, const int* in_sizes, int n_in,
                              void* d_out, int out_size, void* d_ws, size_t ws_size,
                              hipStream_t stream) {
    const float* q = (const float*)d_in[0];
    const float* k = (const float*)d_in[1];
    const float* v = (const float*)d_in[2];
    float* out = (float*)d_out;

    __bf16* Kp = (__bf16*)d_ws;                        // 8 MB
    __bf16* Vp = Kp + (size_t)TB * NH * TT * HD;       // +8 MB

    rope_k_pack<<<dim3((TB * TT * NH * 32) / 256), 256, 0, stream>>>(k, Kp);
    v_pack<<<dim3(TB * NH * (TT / 64)), 256, 0, stream>>>(v, Vp);
    attn_kernel<<<dim3(TB * NH * (TT / 64)), 256, 0, stream>>>(q, Kp, Vp, out);
}

// Round 4
// 164.911 us; speedup vs baseline: 1.9641x; 1.0110x over previous
//
#include <hip/hip_runtime.h>
#include <math.h>

#define TB 2
#define TT 2048
#define NH 16
#define HD 64
#define HSZ 1024

typedef float floatx4 __attribute__((ext_vector_type(4)));
typedef __bf16 bf16x4 __attribute__((ext_vector_type(4)));
typedef __bf16 bf16x8 __attribute__((ext_vector_type(8)));

#define LOG2E  1.4426950408889634f
#define NEGF   (-0.4152410118609203f)   // -log2(10000)/32
#define INV2PI 0.15915494309189535f

// ============ phase 1: fused prep — RoPE-K pack + V transpose-pack ============
// Kp granule per (bh,kt,nt): 2 blocks of 512 bf16. Entry lane=q*16+r holds
//   dims [blk*32+8q,+8) of key t = kt*64 + 4r + nt.
// Vp granule per (bh,kt,hg=h2*4+g): 512 bf16. Entry lane=q*16+r holds
//   V[key=kt*64+h2*32+8q+j][dim=g*16+r], j=0..7.
__global__ __launch_bounds__(256)
void prep_kernel(const float* __restrict__ K, const float* __restrict__ V,
                 __bf16* __restrict__ Kp, __bf16* __restrict__ Vp) {
    int blk = blockIdx.x;               // bh*32 + kt, 1024 blocks
    int kt = blk & 31;
    int bh = blk >> 5;
    int b = bh >> 4, h = bh & 15;
    int tid = threadIdx.x;

    // ---- K part: thread -> (key=tid&63, qq=tid>>6), dims 8qq..+7 (+32) ----
    {
        int key = tid & 63, qq = tid >> 6;
        int tglob = kt * 64 + key;
        const float* krow = K + ((size_t)(b * TT + tglob)) * HSZ + h * HD + qq * 8;
        float x0[8], x1[8];
        *(floatx4*)&x0[0] = *(const floatx4*)&krow[0];
        *(floatx4*)&x0[4] = *(const floatx4*)&krow[4];
        *(floatx4*)&x1[0] = *(const floatx4*)&krow[32];
        *(floatx4*)&x1[4] = *(const floatx4*)&krow[36];
        bf16x8 y0, y1;
        #pragma unroll
        for (int j = 0; j < 8; ++j) {
            float freq = exp2f((float)(qq * 8 + j) * NEGF);
            float rv = (float)tglob * freq * INV2PI;
            rv -= floorf(rv);
            float s = __builtin_amdgcn_sinf(rv);
            float c = __builtin_amdgcn_cosf(rv);
            y0[j] = (__bf16)(x0[j] * c - x1[j] * s);
            y1[j] = (__bf16)(x1[j] * c + x0[j] * s);
        }
        size_t base = ((size_t)blk * 4 + (key & 3)) * 1024 + (size_t)(qq * 16 + (key >> 2)) * 8;
        *(bf16x8*)(Kp + base)       = y0;
        *(bf16x8*)(Kp + base + 512) = y1;
    }

    // ---- V part: transpose 64x64 via LDS ----
    __shared__ __bf16 lt[64][72];       // [dim][key], row 144 B (16B-aligned)
    {
        int vkey = tid >> 2, dg = (tid & 3) * 16;
        const float* vrow = V + ((size_t)(b * TT + kt * 64 + vkey)) * HSZ + h * HD + dg;
        floatx4 v0 = *(const floatx4*)&vrow[0];
        floatx4 v1 = *(const floatx4*)&vrow[4];
        floatx4 v2 = *(const floatx4*)&vrow[8];
        floatx4 v3 = *(const floatx4*)&vrow[12];
        #pragma unroll
        for (int j = 0; j < 4; ++j) {
            lt[dg + j][vkey]      = (__bf16)v0[j];
            lt[dg + 4 + j][vkey]  = (__bf16)v1[j];
            lt[dg + 8 + j][vkey]  = (__bf16)v2[j];
            lt[dg + 12 + j][vkey] = (__bf16)v3[j];
        }
    }
    __syncthreads();
    #pragma unroll
    for (int ss = 0; ss < 2; ++ss) {
        int s = tid + ss * 256;          // 512 fragment entries of 16 B
        int hg = s >> 6;                 // h2*4 + g
        int l = s & 63;
        int lq = l >> 4, lr = l & 15;
        int h2 = hg >> 2, g = hg & 3;
        bf16x8 o = *(const bf16x8*)&lt[g * 16 + lr][h2 * 32 + lq * 8];
        *(bf16x8*)(Vp + (size_t)blk * 4096 + (size_t)hg * 512 + (size_t)l * 8) = o;
    }
}

// ============ phase 2: barrier-free flash attention, static shift, pipelined ============
__global__ __launch_bounds__(128)
void attn_kernel(const float* __restrict__ Q, const __bf16* __restrict__ Kp,
                 const __bf16* __restrict__ Vp, float* __restrict__ Out) {
    int blk = blockIdx.x;               // B*NH*(T/32) = 2048
    int qtile = blk & 63;
    int bh = blk >> 6;
    int b = bh >> 4, h = bh & 15;
    int tid = threadIdx.x;
    int wave = tid >> 6, lane = tid & 63;
    int lane15 = lane & 15, quad = lane >> 4;

    __shared__ __align__(16) __bf16 sP[2][16][72];  // per-wave P round-trip only

    const float scale2 = 0.125f * LOG2E;
    const float slope2 = exp2f(-0.5f * (float)(h + 1)) * LOG2E;
    const float ms     = slope2 * 2047.0f + 20.0f;  // static log2-domain shift

    // ---- Q load + RoPE into A fragments ----
    int t_q = qtile * 32 + wave * 16 + lane15;
    int d0 = quad * 8;
    const float* qrow = Q + ((size_t)(b * TT + t_q) * HSZ) + h * HD;
    float q0[8], q1[8];
    *(floatx4*)&q0[0] = *(const floatx4*)&qrow[d0];
    *(floatx4*)&q0[4] = *(const floatx4*)&qrow[d0 + 4];
    *(floatx4*)&q1[0] = *(const floatx4*)&qrow[d0 + 32];
    *(floatx4*)&q1[4] = *(const floatx4*)&qrow[d0 + 36];
    bf16x8 aQ0, aQ1;
    #pragma unroll
    for (int j = 0; j < 8; ++j) {
        float freq = exp2f((float)(d0 + j) * NEGF);
        float rv = (float)t_q * freq * INV2PI;
        rv -= floorf(rv);
        float s = __builtin_amdgcn_sinf(rv);
        float c = __builtin_amdgcn_cosf(rv);
        aQ0[j] = (__bf16)((q0[j] * c - q1[j] * s) * scale2);
        aQ1[j] = (__bf16)((q1[j] * c + q0[j] * s) * scale2);
    }

    float slk2[4];
    #pragma unroll
    for (int nt = 0; nt < 4; ++nt)
        slk2[nt] = slope2 * (float)(4 * lane15 + nt) - ms;
    const float dstep = slope2 * 64.0f;

    floatx4 O0 = {0.f,0.f,0.f,0.f}, O1 = O0, O2 = O0, O3 = O0;
    float lrow[4] = {0.f, 0.f, 0.f, 0.f};

    const __bf16* Kb = Kp + (size_t)bh * (TT * HD) + (size_t)lane * 8;
    const __bf16* Vb = Vp + (size_t)bh * (TT * HD) + (size_t)lane * 8;

    // prologue: K fragments for kt=0
    bf16x8 bk[4][2];
    #pragma unroll
    for (int nt = 0; nt < 4; ++nt) {
        bk[nt][0] = *(const bf16x8*)(Kb + nt * 1024);
        bk[nt][1] = *(const bf16x8*)(Kb + nt * 1024 + 512);
    }

    for (int kt = 0; kt < TT / 64; ++kt) {
        // ---- V fragment loads for current tile (consumed after QK+softmax) ----
        const __bf16* vbase = Vb + (size_t)kt * 4096;
        bf16x8 bv[2][4];
        #pragma unroll
        for (int hg = 0; hg < 8; ++hg)
            bv[hg >> 2][hg & 3] = *(const bf16x8*)(vbase + hg * 512);

        // ---- QK^T with current K fragments ----
        floatx4 acc[4];
        #pragma unroll
        for (int nt = 0; nt < 4; ++nt) {
            floatx4 a = {0.f,0.f,0.f,0.f};
            a = __builtin_amdgcn_mfma_f32_16x16x32_bf16(aQ0, bk[nt][0], a, 0, 0, 0);
            a = __builtin_amdgcn_mfma_f32_16x16x32_bf16(aQ1, bk[nt][1], a, 0, 0, 0);
            acc[nt] = a;
        }

        // ---- prefetch K fragments for next tile (latency hidden by softmax+PV) ----
        int ktn = (kt + 1 < TT / 64) ? kt + 1 : kt;
        const __bf16* kbase = Kb + (size_t)ktn * 4096;
        #pragma unroll
        for (int nt = 0; nt < 4; ++nt) {
            bk[nt][0] = *(const bf16x8*)(kbase + nt * 1024);
            bk[nt][1] = *(const bf16x8*)(kbase + nt * 1024 + 512);
        }

        // ---- bias + exp2 (base-2, static shift; no running max) ----
        float P[4][4];
        float biask = dstep * (float)kt;
        #pragma unroll
        for (int nt = 0; nt < 4; ++nt) {
            float bias = slk2[nt] + biask;
            #pragma unroll
            for (int r = 0; r < 4; ++r)
                P[nt][r] = __builtin_amdgcn_exp2f(acc[nt][r] + bias);
        }

        // ---- P -> LDS (one b64 per row), accumulate row sums ----
        #pragma unroll
        for (int r = 0; r < 4; ++r) {
            lrow[r] += (P[0][r] + P[1][r]) + (P[2][r] + P[3][r]);
            bf16x4 pp;
            pp[0] = (__bf16)P[0][r]; pp[1] = (__bf16)P[1][r];
            pp[2] = (__bf16)P[2][r]; pp[3] = (__bf16)P[3][r];
            *(bf16x4*)&sP[wave][quad * 4 + r][4 * lane15] = pp;
        }

        // ---- PV: O[16q][64d] += P(16x64) * V(64x64) ----
        #pragma unroll
        for (int h2 = 0; h2 < 2; ++h2) {
            bf16x8 aP = *(const bf16x8*)&sP[wave][lane15][h2 * 32 + quad * 8];
            O0 = __builtin_amdgcn_mfma_f32_16x16x32_bf16(aP, bv[h2][0], O0, 0, 0, 0);
            O1 = __builtin_amdgcn_mfma_f32_16x16x32_bf16(aP, bv[h2][1], O1, 0, 0, 0);
            O2 = __builtin_amdgcn_mfma_f32_16x16x32_bf16(aP, bv[h2][2], O2, 0, 0, 0);
            O3 = __builtin_amdgcn_mfma_f32_16x16x32_bf16(aP, bv[h2][3], O3, 0, 0, 0);
        }
    }

    // ---- epilogue: reduce l across 16 lanes, normalize, store ----
    int q_glb = qtile * 32 + wave * 16 + quad * 4;
    #pragma unroll
    for (int r = 0; r < 4; ++r) {
        float l = lrow[r];
        l += __shfl_xor(l, 1);
        l += __shfl_xor(l, 2);
        l += __shfl_xor(l, 4);
        l += __shfl_xor(l, 8);
        float inv = 1.0f / l;
        size_t base = ((size_t)(b * TT + q_glb + r) * HSZ) + h * HD + lane15;
        Out[base +  0] = O0[r] * inv;
        Out[base + 16] = O1[r] * inv;
        Out[base + 32] = O2[r] * inv;
        Out[base + 48] = O3[r] * inv;
    }
}

extern "C" void kernel_launch(void* const* d_in, const int* in_sizes, int n_in,
                              void* d_out, int out_size, void* d_ws, size_t ws_size,
                              hipStream_t stream) {
    const float* q = (const float*)d_in[0];
    const float* k = (const float*)d_in[1];
    const float* v = (const float*)d_in[2];
    float* out = (float*)d_out;

    __bf16* Kp = (__bf16*)d_ws;                        // 8 MB
    __bf16* Vp = Kp + (size_t)TB * NH * TT * HD;       // +8 MB

    prep_kernel<<<dim3(TB * NH * (TT / 64)), 256, 0, stream>>>(k, v, Kp, Vp);
    attn_kernel<<<dim3(TB * NH * (TT / 32)), 128, 0, stream>>>(q, Kp, Vp, out);
}